// Round 1
// baseline (2401.227 us; speedup 1.0000x reference)
//
#include <hip/hip_runtime.h>

#define NN 50000
#define EE 800000
#define DD 64
#define GG 512

// ---------------------------------------------------------------------------
// z[dst] += h[src] for every edge. 16 threads per edge, float4 per thread.
// Atomics are device-scope hardware fadd (relaxed, agent scope -> global_atomic_add_f32).
// ---------------------------------------------------------------------------
__global__ __launch_bounds__(256) void scatter_kernel(const float* __restrict__ h,
                                                      const int* __restrict__ ei,
                                                      float* __restrict__ z) {
    const int stride = gridDim.x * blockDim.x;
    const int total = EE * 16;
    for (int t = blockIdx.x * blockDim.x + threadIdx.x; t < total; t += stride) {
        const int e = t >> 4;
        const int c = (t & 15) << 2;
        const int src = ei[e];
        const int dst = ei[EE + e];
        const float4 v = *(const float4*)(h + src * 64 + c);
        float* p = z + dst * 64 + c;
        __hip_atomic_fetch_add(p + 0, v.x, __ATOMIC_RELAXED, __HIP_MEMORY_SCOPE_AGENT);
        __hip_atomic_fetch_add(p + 1, v.y, __ATOMIC_RELAXED, __HIP_MEMORY_SCOPE_AGENT);
        __hip_atomic_fetch_add(p + 2, v.z, __ATOMIC_RELAXED, __HIP_MEMORY_SCOPE_AGENT);
        __hip_atomic_fetch_add(p + 3, v.w, __ATOMIC_RELAXED, __HIP_MEMORY_SCOPE_AGENT);
    }
}

// ---------------------------------------------------------------------------
// t = relu(relu((z+h) @ wa + ba) @ wb + bb), plus per-block partial BN stats.
// One wave per row (lane = output feature). Weights staged in LDS.
// partials[b*128 + f]      = sum over this block's rows of t[:,f]
// partials[b*128 + 64 + f] = sum of t[:,f]^2
// ---------------------------------------------------------------------------
__global__ __launch_bounds__(256) void mlp_kernel(const float* __restrict__ z,
                                                  const float* __restrict__ h,
                                                  const float* __restrict__ wa,
                                                  const float* __restrict__ ba,
                                                  const float* __restrict__ wb,
                                                  const float* __restrict__ bb,
                                                  float* __restrict__ t,
                                                  float* __restrict__ partials) {
    __shared__ float lwa[64 * 64];
    __shared__ float lwb[64 * 64];
    __shared__ float lb[128];
    __shared__ float rowbuf[4][64];
    __shared__ float redbuf[512];

    for (int i = threadIdx.x; i < 4096; i += 256) {
        lwa[i] = wa[i];
        lwb[i] = wb[i];
    }
    if (threadIdx.x < 64) lb[threadIdx.x] = ba[threadIdx.x];
    else if (threadIdx.x < 128) lb[threadIdx.x] = bb[threadIdx.x - 64];
    __syncthreads();

    const int wave = threadIdx.x >> 6;
    const int lane = threadIdx.x & 63;

    float fsum = 0.f, fsq = 0.f;
    for (int row = blockIdx.x * 4 + wave; row < NN; row += gridDim.x * 4) {
        const float v = z[row * 64 + lane] + h[row * 64 + lane];
        rowbuf[wave][lane] = v;   // wave-synchronous: same-wave LDS ops are ordered
        float acc = lb[lane];
        #pragma unroll
        for (int k = 0; k < 64; ++k)
            acc = fmaf(rowbuf[wave][k], lwa[k * 64 + lane], acc);
        acc = fmaxf(acc, 0.f);
        rowbuf[wave][lane] = acc; // ordered after the reads above (same object)
        float acc2 = lb[64 + lane];
        #pragma unroll
        for (int k = 0; k < 64; ++k)
            acc2 = fmaf(rowbuf[wave][k], lwb[k * 64 + lane], acc2);
        acc2 = fmaxf(acc2, 0.f);
        t[row * 64 + lane] = acc2;
        fsum += acc2;
        fsq += acc2 * acc2;
    }

    redbuf[wave * 64 + lane] = fsum;
    redbuf[256 + wave * 64 + lane] = fsq;
    __syncthreads();
    if (threadIdx.x < 128) {
        const int f = threadIdx.x & 63;
        const int base = (threadIdx.x < 64) ? 0 : 256;
        const float s = redbuf[base + f] + redbuf[base + 64 + f] +
                        redbuf[base + 128 + f] + redbuf[base + 192 + f];
        partials[blockIdx.x * 128 + threadIdx.x] = s;
    }
}

// ---------------------------------------------------------------------------
// Reduce 512 partial blocks -> mean/var -> fused scale/shift:
// ss[f] = gamma*rsqrt(var+eps); ss[64+f] = beta - mean*scale
// ---------------------------------------------------------------------------
__global__ __launch_bounds__(1024) void finalize_kernel(const float* __restrict__ partials,
                                                        const float* __restrict__ g,
                                                        const float* __restrict__ be,
                                                        float* __restrict__ ss) {
    __shared__ float red[1024];
    const int f = threadIdx.x & 127;
    const int seg = threadIdx.x >> 7;  // 0..7
    float s = 0.f;
    for (int b = seg; b < 512; b += 8) s += partials[b * 128 + f];
    red[threadIdx.x] = s;
    __syncthreads();
    if (threadIdx.x < 128) {
        float tot = 0.f;
        #pragma unroll
        for (int k = 0; k < 8; ++k) tot += red[k * 128 + threadIdx.x];
        red[threadIdx.x] = tot;
    }
    __syncthreads();
    if (threadIdx.x < 64) {
        const float mean = red[threadIdx.x] * (1.0f / NN);
        const float var = red[64 + threadIdx.x] * (1.0f / NN) - mean * mean;
        const float scl = g[threadIdx.x] * rsqrtf(var + 1e-5f);
        ss[threadIdx.x] = scl;
        ss[64 + threadIdx.x] = be[threadIdx.x] - mean * scl;
    }
}

// ---------------------------------------------------------------------------
// h = t * scale + shift (elementwise, float4)
// ---------------------------------------------------------------------------
__global__ __launch_bounds__(256) void norm_kernel(const float* __restrict__ t,
                                                   const float* __restrict__ ss,
                                                   float* __restrict__ h) {
    const int tid = blockIdx.x * blockDim.x + threadIdx.x;  // NN*16 total
    if (tid >= NN * 16) return;
    const int c = (tid & 15) << 2;
    const float4 v = *(const float4*)(t + tid * 4);
    float4 o;
    o.x = v.x * ss[c + 0] + ss[64 + c + 0];
    o.y = v.y * ss[c + 1] + ss[64 + c + 1];
    o.z = v.z * ss[c + 2] + ss[64 + c + 2];
    o.w = v.w * ss[c + 3] + ss[64 + c + 3];
    *(float4*)(h + tid * 4) = o;
}

// ---------------------------------------------------------------------------
// xpool[batch[n]] += h[n]  (batch is sorted; plain atomics are fine at 3.2M ops)
// ---------------------------------------------------------------------------
__global__ __launch_bounds__(256) void pool_kernel(const float* __restrict__ h,
                                                   const int* __restrict__ batch,
                                                   float* __restrict__ xpool) {
    const int tid = blockIdx.x * blockDim.x + threadIdx.x;  // NN*16 total
    if (tid >= NN * 16) return;
    const int n = tid >> 4;
    const int c = (tid & 15) << 2;
    const int g = batch[n];
    const float4 v = *(const float4*)(h + n * 64 + c);
    float* p = xpool + g * 64 + c;
    __hip_atomic_fetch_add(p + 0, v.x, __ATOMIC_RELAXED, __HIP_MEMORY_SCOPE_AGENT);
    __hip_atomic_fetch_add(p + 1, v.y, __ATOMIC_RELAXED, __HIP_MEMORY_SCOPE_AGENT);
    __hip_atomic_fetch_add(p + 2, v.z, __ATOMIC_RELAXED, __HIP_MEMORY_SCOPE_AGENT);
    __hip_atomic_fetch_add(p + 3, v.w, __ATOMIC_RELAXED, __HIP_MEMORY_SCOPE_AGENT);
}

// ---------------------------------------------------------------------------
// mid[g][m] = xpool[g] . w_lin0[:,m] + b_lin0[m]          (512 x 128)
// ---------------------------------------------------------------------------
__global__ __launch_bounds__(256) void lin0_kernel(const float* __restrict__ xpool,
                                                   const float* __restrict__ w,
                                                   const float* __restrict__ b,
                                                   float* __restrict__ mid) {
    const int tid = blockIdx.x * blockDim.x + threadIdx.x;  // GG*128
    if (tid >= GG * 128) return;
    const int g = tid >> 7;
    const int m = tid & 127;
    float acc = b[m];
    #pragma unroll 8
    for (int k = 0; k < 64; ++k) acc = fmaf(xpool[g * 64 + k], w[k * 128 + m], acc);
    mid[tid] = acc;
}

// ---------------------------------------------------------------------------
// out[g][j] = relu(mid[g] . w_fc1[:,j] + b_fc1[j])        (512 x 64)
// ---------------------------------------------------------------------------
__global__ __launch_bounds__(256) void fc1_kernel(const float* __restrict__ mid,
                                                  const float* __restrict__ w,
                                                  const float* __restrict__ b,
                                                  float* __restrict__ out) {
    const int tid = blockIdx.x * blockDim.x + threadIdx.x;  // GG*64
    if (tid >= GG * 64) return;
    const int g = tid >> 6;
    const int j = tid & 63;
    float acc = b[j];
    #pragma unroll 8
    for (int k = 0; k < 128; ++k) acc = fmaf(mid[g * 128 + k], w[k * 64 + j], acc);
    out[tid] = fmaxf(acc, 0.f);
}

extern "C" void kernel_launch(void* const* d_in, const int* in_sizes, int n_in,
                              void* d_out, int out_size, void* d_ws, size_t ws_size,
                              hipStream_t stream) {
    const float* x = (const float*)d_in[0];
    const int* ei = (const int*)d_in[1];
    const int* batch = (const int*)d_in[2];

    float* ws = (float*)d_ws;
    float* z        = ws;                       // NN*64 = 3,200,000
    float* t        = ws + 3200000;             // NN*64
    float* h        = ws + 6400000;             // NN*64
    float* partials = ws + 9600000;             // 512*128 = 65,536
    float* ss       = partials + 65536;         // 128
    float* xpool    = ss + 128;                 // GG*64 = 32,768
    float* mid      = xpool + 32768;            // GG*128 = 65,536

    const float* hcur = x;
    for (int l = 0; l < 3; ++l) {
        const float* wa = (const float*)d_in[3 + l * 6 + 0];
        const float* ba = (const float*)d_in[3 + l * 6 + 1];
        const float* wb = (const float*)d_in[3 + l * 6 + 2];
        const float* bb = (const float*)d_in[3 + l * 6 + 3];
        const float* ga = (const float*)d_in[3 + l * 6 + 4];
        const float* be = (const float*)d_in[3 + l * 6 + 5];

        hipMemsetAsync(z, 0, (size_t)NN * 64 * sizeof(float), stream);
        scatter_kernel<<<8192, 256, 0, stream>>>(hcur, ei, z);
        mlp_kernel<<<512, 256, 0, stream>>>(z, hcur, wa, ba, wb, bb, t, partials);
        finalize_kernel<<<1, 1024, 0, stream>>>(partials, ga, be, ss);
        norm_kernel<<<(NN * 16 + 255) / 256, 256, 0, stream>>>(t, ss, h);
        hcur = h;
    }

    hipMemsetAsync(xpool, 0, (size_t)GG * 64 * sizeof(float), stream);
    pool_kernel<<<(NN * 16 + 255) / 256, 256, 0, stream>>>(h, batch, xpool);
    lin0_kernel<<<(GG * 128 + 255) / 256, 256, 0, stream>>>(
        xpool, (const float*)d_in[21], (const float*)d_in[22], mid);
    fc1_kernel<<<(GG * 64 + 255) / 256, 256, 0, stream>>>(
        mid, (const float*)d_in[23], (const float*)d_in[24], (float*)d_out);
}

// Round 2
// 643.254 us; speedup vs baseline: 3.7329x; 3.7329x over previous
//
#include <hip/hip_runtime.h>

#define NN 50000
#define EE 800000
#define DD 64
#define GG 512
#define MLP_GRID 1024

// ===========================================================================
// CSR build over dst: histogram -> exclusive scan -> fill.
// Only int atomics (1.6M total) -- replaces 153.6M float atomics per call.
// ===========================================================================
__global__ __launch_bounds__(256) void hist_kernel(const int* __restrict__ ei,
                                                   int* __restrict__ counts) {
    const int e = blockIdx.x * blockDim.x + threadIdx.x;
    if (e < EE) atomicAdd(&counts[ei[EE + e]], 1);
}

// Single-block scan of the 50k histogram -> rowptr (exclusive prefix) + cursor copy.
__global__ __launch_bounds__(1024) void scan_kernel(int* __restrict__ rowptr,
                                                    int* __restrict__ cursor) {
    __shared__ int sums[1024];
    const int chunk = 49;  // 1024*49 >= 50000
    const int beg = threadIdx.x * chunk;
    const int end = min(beg + chunk, NN);
    int s = 0;
    for (int i = beg; i < end; ++i) s += rowptr[i];
    sums[threadIdx.x] = s;
    __syncthreads();
    for (int off = 1; off < 1024; off <<= 1) {
        const int v = sums[threadIdx.x];
        const int add = (threadIdx.x >= (unsigned)off) ? sums[threadIdx.x - off] : 0;
        __syncthreads();
        sums[threadIdx.x] = v + add;
        __syncthreads();
    }
    int base = (threadIdx.x == 0) ? 0 : sums[threadIdx.x - 1];
    for (int i = beg; i < end; ++i) {
        const int c = rowptr[i];
        rowptr[i] = base;
        cursor[i] = base;
        base += c;
    }
    if (threadIdx.x == 1023) rowptr[NN] = EE;
}

__global__ __launch_bounds__(256) void fill_kernel(const int* __restrict__ ei,
                                                   int* __restrict__ cursor,
                                                   int* __restrict__ col) {
    const int e = blockIdx.x * blockDim.x + threadIdx.x;
    if (e < EE) {
        const int pos = atomicAdd(&cursor[ei[EE + e]], 1);
        col[pos] = ei[e];
    }
}

// ===========================================================================
// Fused: agg = sum_{src in CSR row} h[src]; v = agg + h[row];
//        t = relu(relu(v @ wa + ba) @ wb + bb); plus per-block BN partials.
// One wave per row, lane = feature. No float atomics anywhere.
// ===========================================================================
__global__ __launch_bounds__(256) void mlp_kernel(const float* __restrict__ h,
                                                  const int* __restrict__ rowptr,
                                                  const int* __restrict__ col,
                                                  const float* __restrict__ wa,
                                                  const float* __restrict__ ba,
                                                  const float* __restrict__ wb,
                                                  const float* __restrict__ bb,
                                                  float* __restrict__ t,
                                                  float* __restrict__ partials) {
    __shared__ float lwa[64 * 64];
    __shared__ float lwb[64 * 64];
    __shared__ float lb[128];
    __shared__ float rowbuf[4][64];
    __shared__ float redbuf[512];

    for (int i = threadIdx.x; i < 4096; i += 256) {
        lwa[i] = wa[i];
        lwb[i] = wb[i];
    }
    if (threadIdx.x < 64) lb[threadIdx.x] = ba[threadIdx.x];
    else if (threadIdx.x < 128) lb[threadIdx.x] = bb[threadIdx.x - 64];
    __syncthreads();

    const int wave = threadIdx.x >> 6;
    const int lane = threadIdx.x & 63;

    float fsum = 0.f, fsq = 0.f;
    for (int row = blockIdx.x * 4 + wave; row < NN; row += gridDim.x * 4) {
        // ---- gather (register accumulation, 4-way ILP) ----
        float v = h[row * 64 + lane];
        const int beg = rowptr[row];
        const int end = rowptr[row + 1];
        float a0 = 0.f, a1 = 0.f, a2 = 0.f, a3 = 0.f;
        int j = beg;
        for (; j + 4 <= end; j += 4) {
            const int s0 = col[j], s1 = col[j + 1], s2 = col[j + 2], s3 = col[j + 3];
            a0 += h[s0 * 64 + lane];
            a1 += h[s1 * 64 + lane];
            a2 += h[s2 * 64 + lane];
            a3 += h[s3 * 64 + lane];
        }
        for (; j < end; ++j) a0 += h[col[j] * 64 + lane];
        v += (a0 + a1) + (a2 + a3);

        // ---- MLP ----
        rowbuf[wave][lane] = v;  // wave-synchronous LDS, ordered within wave
        float acc = lb[lane];
        #pragma unroll
        for (int k = 0; k < 64; ++k)
            acc = fmaf(rowbuf[wave][k], lwa[k * 64 + lane], acc);
        acc = fmaxf(acc, 0.f);
        rowbuf[wave][lane] = acc;
        float acc2 = lb[64 + lane];
        #pragma unroll
        for (int k = 0; k < 64; ++k)
            acc2 = fmaf(rowbuf[wave][k], lwb[k * 64 + lane], acc2);
        acc2 = fmaxf(acc2, 0.f);
        t[row * 64 + lane] = acc2;
        fsum += acc2;
        fsq += acc2 * acc2;
    }

    redbuf[wave * 64 + lane] = fsum;
    redbuf[256 + wave * 64 + lane] = fsq;
    __syncthreads();
    if (threadIdx.x < 128) {
        const int f = threadIdx.x & 63;
        const int base = (threadIdx.x < 64) ? 0 : 256;
        const float s = redbuf[base + f] + redbuf[base + 64 + f] +
                        redbuf[base + 128 + f] + redbuf[base + 192 + f];
        partials[blockIdx.x * 128 + threadIdx.x] = s;
    }
}

// ===========================================================================
// Reduce MLP_GRID partial blocks -> fused BN scale/shift
// ===========================================================================
__global__ __launch_bounds__(1024) void finalize_kernel(const float* __restrict__ partials,
                                                        const float* __restrict__ g,
                                                        const float* __restrict__ be,
                                                        float* __restrict__ ss) {
    __shared__ float red[1024];
    const int f = threadIdx.x & 127;
    const int seg = threadIdx.x >> 7;  // 0..7
    float s = 0.f;
    for (int b = seg; b < MLP_GRID; b += 8) s += partials[b * 128 + f];
    red[threadIdx.x] = s;
    __syncthreads();
    if (threadIdx.x < 128) {
        float tot = 0.f;
        #pragma unroll
        for (int k = 0; k < 8; ++k) tot += red[k * 128 + threadIdx.x];
        red[threadIdx.x] = tot;
    }
    __syncthreads();
    if (threadIdx.x < 64) {
        const float mean = red[threadIdx.x] * (1.0f / NN);
        const float var = red[64 + threadIdx.x] * (1.0f / NN) - mean * mean;
        const float scl = g[threadIdx.x] * rsqrtf(var + 1e-5f);
        ss[threadIdx.x] = scl;
        ss[64 + threadIdx.x] = be[threadIdx.x] - mean * scl;
    }
}

// ===========================================================================
// h = t * scale + shift (elementwise, float4)
// ===========================================================================
__global__ __launch_bounds__(256) void norm_kernel(const float* __restrict__ t,
                                                   const float* __restrict__ ss,
                                                   float* __restrict__ h) {
    const int tid = blockIdx.x * blockDim.x + threadIdx.x;  // NN*16 total
    if (tid >= NN * 16) return;
    const int c = (tid & 15) << 2;
    const float4 v = *(const float4*)(t + tid * 4);
    float4 o;
    o.x = v.x * ss[c + 0] + ss[64 + c + 0];
    o.y = v.y * ss[c + 1] + ss[64 + c + 1];
    o.z = v.z * ss[c + 2] + ss[64 + c + 2];
    o.w = v.w * ss[c + 3] + ss[64 + c + 3];
    *(float4*)(h + tid * 4) = o;
}

// ===========================================================================
// Pool: batch is SORTED -> per-wave segment accumulate, atomic only at group
// boundaries (~115k atomics instead of 3.2M).
// ===========================================================================
__global__ __launch_bounds__(256) void pool_kernel(const float* __restrict__ h,
                                                   const int* __restrict__ batch,
                                                   float* __restrict__ xpool) {
    const int wv = (blockIdx.x * 256 + threadIdx.x) >> 6;  // global wave id
    const int lane = threadIdx.x & 63;
    const int r0 = wv * 64;
    if (r0 >= NN) return;
    const int r1 = min(r0 + 64, NN);
    int gprev = batch[r0];
    float acc = 0.f;
    for (int r = r0; r < r1; ++r) {
        const int g = batch[r];
        if (g != gprev) {
            __hip_atomic_fetch_add(&xpool[gprev * 64 + lane], acc,
                                   __ATOMIC_RELAXED, __HIP_MEMORY_SCOPE_AGENT);
            acc = 0.f;
            gprev = g;
        }
        acc += h[r * 64 + lane];
    }
    __hip_atomic_fetch_add(&xpool[gprev * 64 + lane], acc,
                           __ATOMIC_RELAXED, __HIP_MEMORY_SCOPE_AGENT);
}

// ===========================================================================
// Head
// ===========================================================================
__global__ __launch_bounds__(256) void lin0_kernel(const float* __restrict__ xpool,
                                                   const float* __restrict__ w,
                                                   const float* __restrict__ b,
                                                   float* __restrict__ mid) {
    const int tid = blockIdx.x * blockDim.x + threadIdx.x;  // GG*128
    if (tid >= GG * 128) return;
    const int g = tid >> 7;
    const int m = tid & 127;
    float acc = b[m];
    #pragma unroll 8
    for (int k = 0; k < 64; ++k) acc = fmaf(xpool[g * 64 + k], w[k * 128 + m], acc);
    mid[tid] = acc;
}

__global__ __launch_bounds__(256) void fc1_kernel(const float* __restrict__ mid,
                                                  const float* __restrict__ w,
                                                  const float* __restrict__ b,
                                                  float* __restrict__ out) {
    const int tid = blockIdx.x * blockDim.x + threadIdx.x;  // GG*64
    if (tid >= GG * 64) return;
    const int g = tid >> 6;
    const int j = tid & 63;
    float acc = b[j];
    #pragma unroll 8
    for (int k = 0; k < 128; ++k) acc = fmaf(mid[g * 128 + k], w[k * 64 + j], acc);
    out[tid] = fmaxf(acc, 0.f);
}

extern "C" void kernel_launch(void* const* d_in, const int* in_sizes, int n_in,
                              void* d_out, int out_size, void* d_ws, size_t ws_size,
                              hipStream_t stream) {
    const float* x = (const float*)d_in[0];
    const int* ei = (const int*)d_in[1];
    const int* batch = (const int*)d_in[2];

    // ---- workspace layout (all offsets keep 16B alignment for float4 use) ----
    int* rowptr = (int*)d_ws;                 // 50001 ints (pad to 50004)
    int* cursor = rowptr + 50004;             // 50000 ints
    int* col    = cursor + 50000;             // 800000 ints
    float* fbase = (float*)d_ws + 900004;     // 16B aligned (900004*4 % 16 == 0)
    float* t        = fbase;                  // NN*64 = 3,200,000
    float* h        = t + 3200000;            // NN*64
    float* partials = h + 3200000;            // MLP_GRID*128 = 131072
    float* ss       = partials + 131072;      // 128
    float* xpool    = ss + 128;               // GG*64 = 32768
    float* mid      = xpool + 32768;          // GG*128 = 65536

    // ---- CSR build (once, reused for all 3 layers) ----
    hipMemsetAsync(rowptr, 0, 50001 * sizeof(int), stream);
    hist_kernel<<<(EE + 255) / 256, 256, 0, stream>>>(ei, rowptr);
    scan_kernel<<<1, 1024, 0, stream>>>(rowptr, cursor);
    fill_kernel<<<(EE + 255) / 256, 256, 0, stream>>>(ei, cursor, col);

    const float* hcur = x;
    for (int l = 0; l < 3; ++l) {
        const float* wa = (const float*)d_in[3 + l * 6 + 0];
        const float* ba = (const float*)d_in[3 + l * 6 + 1];
        const float* wb = (const float*)d_in[3 + l * 6 + 2];
        const float* bb = (const float*)d_in[3 + l * 6 + 3];
        const float* ga = (const float*)d_in[3 + l * 6 + 4];
        const float* be = (const float*)d_in[3 + l * 6 + 5];

        mlp_kernel<<<MLP_GRID, 256, 0, stream>>>(hcur, rowptr, col, wa, ba, wb, bb, t, partials);
        finalize_kernel<<<1, 1024, 0, stream>>>(partials, ga, be, ss);
        norm_kernel<<<(NN * 16 + 255) / 256, 256, 0, stream>>>(t, ss, h);
        hcur = h;
    }

    hipMemsetAsync(xpool, 0, (size_t)GG * 64 * sizeof(float), stream);
    pool_kernel<<<((NN + 63) / 64 + 3) / 4, 256, 0, stream>>>(h, batch, xpool);
    lin0_kernel<<<(GG * 128 + 255) / 256, 256, 0, stream>>>(
        xpool, (const float*)d_in[21], (const float*)d_in[22], mid);
    fc1_kernel<<<(GG * 64 + 255) / 256, 256, 0, stream>>>(
        mid, (const float*)d_in[23], (const float*)d_in[24], (float*)d_out);
}

// Round 3
// 621.006 us; speedup vs baseline: 3.8667x; 1.0358x over previous
//
#include <hip/hip_runtime.h>

#define NN 50000
#define EE 800000
#define DD 64
#define GG 512
#define TILES 782          // ceil(NN/64)
#define SCAN_BLOCKS 98     // ceil(NN/512)

// ===========================================================================
// CSR build: histogram -> 2-level exclusive scan -> fill. Int atomics only.
// ===========================================================================
__global__ __launch_bounds__(256) void hist_kernel(const int* __restrict__ ei,
                                                   int* __restrict__ counts) {
    const int e = blockIdx.x * blockDim.x + threadIdx.x;
    if (e < EE) atomicAdd(&counts[ei[EE + e]], 1);
}

// Per-block exclusive scan of 512-element chunks + block sums
__global__ __launch_bounds__(512) void scan1_kernel(const int* __restrict__ counts,
                                                    int* __restrict__ scanned,
                                                    int* __restrict__ bsum) {
    __shared__ int buf[512];
    const int i = blockIdx.x * 512 + threadIdx.x;
    const int v = (i < NN) ? counts[i] : 0;
    buf[threadIdx.x] = v;
    __syncthreads();
    for (int off = 1; off < 512; off <<= 1) {
        const int add = (threadIdx.x >= off) ? buf[threadIdx.x - off] : 0;
        __syncthreads();
        buf[threadIdx.x] += add;
        __syncthreads();
    }
    if (i < NN) scanned[i] = buf[threadIdx.x] - v;   // exclusive
    if (threadIdx.x == 511) bsum[blockIdx.x] = buf[511];
}

// Add block offsets -> rowptr + cursor
__global__ __launch_bounds__(512) void scan2_kernel(const int* __restrict__ scanned,
                                                    const int* __restrict__ bsum,
                                                    int* __restrict__ rowptr,
                                                    int* __restrict__ cursor) {
    __shared__ int red[128];
    if (threadIdx.x < 128)
        red[threadIdx.x] = (threadIdx.x < blockIdx.x) ? bsum[threadIdx.x] : 0;
    __syncthreads();
    for (int off = 64; off > 0; off >>= 1) {
        if (threadIdx.x < off) red[threadIdx.x] += red[threadIdx.x + off];
        __syncthreads();
    }
    const int offset = red[0];
    const int i = blockIdx.x * 512 + threadIdx.x;
    if (i < NN) {
        const int p = scanned[i] + offset;
        rowptr[i] = p;
        cursor[i] = p;
    }
    if (blockIdx.x == 0 && threadIdx.x == 0) rowptr[NN] = EE;
}

__global__ __launch_bounds__(256) void fill_kernel(const int* __restrict__ ei,
                                                   int* __restrict__ cursor,
                                                   int* __restrict__ col) {
    const int e = blockIdx.x * blockDim.x + threadIdx.x;
    if (e < EE) {
        const int pos = atomicAdd(&cursor[ei[EE + e]], 1);
        col[pos] = ei[e];
    }
}

// ===========================================================================
// Gather with fused BN affine of the PREVIOUS layer:
//   z[i] = scl .* (t[i] + sum_{j in N(i)} t[j]) + (deg_i+1) .* shift
// (affine commutes with the segment sum; layer 1 uses identity via apply=0)
// One wave per row, lane = feature (coalesced 256B per neighbor).
// ===========================================================================
__global__ __launch_bounds__(256) void gather_kernel(const float* __restrict__ hin,
                                                     const int* __restrict__ rowptr,
                                                     const int* __restrict__ col,
                                                     const float* __restrict__ ss,
                                                     const int apply,
                                                     float* __restrict__ z) {
    const int wv = (blockIdx.x * 256 + threadIdx.x) >> 6;
    const int lane = threadIdx.x & 63;
    const int nwaves = (gridDim.x * 256) >> 6;
    const float scl = apply ? ss[lane] : 1.0f;
    const float sft = apply ? ss[64 + lane] : 0.0f;
    for (int row = wv; row < NN; row += nwaves) {
        const int beg = rowptr[row];
        const int end = rowptr[row + 1];
        float a0 = hin[row * 64 + lane], a1 = 0.f, a2 = 0.f, a3 = 0.f;
        int j = beg;
        for (; j + 4 <= end; j += 4) {
            const int s0 = col[j], s1 = col[j + 1], s2 = col[j + 2], s3 = col[j + 3];
            a0 += hin[s0 * 64 + lane];
            a1 += hin[s1 * 64 + lane];
            a2 += hin[s2 * 64 + lane];
            a3 += hin[s3 * 64 + lane];
        }
        for (; j < end; ++j) a0 += hin[col[j] * 64 + lane];
        const float sum = (a0 + a1) + (a2 + a3);
        z[row * 64 + lane] = fmaf(sum, scl, (float)(end - beg + 1) * sft);
    }
}

// ===========================================================================
// Register-tiled MLP: one wave per 64-row tile, lane = row.
// acc[64] in VGPRs; weights are wave-uniform loads (scalar path, no LDS);
// dynamic-k input reads via lane-private LDS row (stride 65, conflict-free).
// Also emits per-tile BN partial sums via in-LDS transpose read.
// t = relu(relu(z@wa+ba)@wb+bb)
// ===========================================================================
__global__ __launch_bounds__(64) void mlp_kernel(const float* __restrict__ z,
                                                 const float* __restrict__ wa,
                                                 const float* __restrict__ ba,
                                                 const float* __restrict__ wb,
                                                 const float* __restrict__ bb,
                                                 float* __restrict__ t,
                                                 float* __restrict__ partials) {
    __shared__ float tile[64 * 65];
    const int lane = threadIdx.x;      // 0..63, one wave per block
    const int row0 = blockIdx.x * 64;

    // ---- stage z[row0:row0+64, :] into LDS rows (coalesced float4 reads) ----
    #pragma unroll
    for (int m = 0; m < 16; ++m) {
        const int q = m * 256 + lane * 4;
        const int r = q >> 6, f = q & 63;
        const int grow = row0 + r;
        float4 v = make_float4(0.f, 0.f, 0.f, 0.f);
        if (grow < NN) v = *(const float4*)(z + grow * 64 + f);
        tile[r * 65 + f + 0] = v.x;
        tile[r * 65 + f + 1] = v.y;
        tile[r * 65 + f + 2] = v.z;
        tile[r * 65 + f + 3] = v.w;
    }
    // single wave: same-wave LDS ops are ordered; no barriers needed anywhere

    float acc[64];
    #pragma unroll
    for (int f = 0; f < 64; ++f) acc[f] = ba[f];
    #pragma unroll 8
    for (int k = 0; k < 64; ++k) {
        const float v = tile[lane * 65 + k];       // lane-private row
        #pragma unroll
        for (int f = 0; f < 64; ++f)
            acc[f] = fmaf(v, wa[k * 64 + f], acc[f]);   // uniform weight -> s_load
    }
    // relu -> back to lane-private LDS row (enables dynamic-k reads for mat B)
    #pragma unroll
    for (int f = 0; f < 64; ++f) tile[lane * 65 + f] = fmaxf(acc[f], 0.f);

    #pragma unroll
    for (int f = 0; f < 64; ++f) acc[f] = bb[f];
    #pragma unroll 8
    for (int k = 0; k < 64; ++k) {
        const float v = tile[lane * 65 + k];
        #pragma unroll
        for (int f = 0; f < 64; ++f)
            acc[f] = fmaf(v, wb[k * 64 + f], acc[f]);
    }
    // t = relu(acc) -> LDS (for stats transpose + coalesced writeback)
    #pragma unroll
    for (int f = 0; f < 64; ++f) tile[lane * 65 + f] = fmaxf(acc[f], 0.f);

    // ---- BN partials: lane = feature, sum over this tile's valid rows ----
    const int nrows = min(64, NN - row0);
    float s = 0.f, sq = 0.f;
    #pragma unroll 8
    for (int r = 0; r < nrows; ++r) {
        const float v = tile[r * 65 + lane];       // bank (r+lane)&31: conflict-free
        s += v;
        sq += v * v;
    }
    partials[blockIdx.x * 128 + lane] = s;
    partials[blockIdx.x * 128 + 64 + lane] = sq;

    // ---- coalesced writeback ----
    #pragma unroll
    for (int m = 0; m < 16; ++m) {
        const int q = m * 256 + lane * 4;
        const int r = q >> 6, f = q & 63;
        const int grow = row0 + r;
        if (grow < NN) {
            float4 v;
            v.x = tile[r * 65 + f + 0];
            v.y = tile[r * 65 + f + 1];
            v.z = tile[r * 65 + f + 2];
            v.w = tile[r * 65 + f + 3];
            *(float4*)(t + grow * 64 + f) = v;
        }
    }
}

// ===========================================================================
// Reduce TILES partial blocks -> fused BN scale/shift
// ===========================================================================
__global__ __launch_bounds__(1024) void finalize_kernel(const float* __restrict__ partials,
                                                        const float* __restrict__ g,
                                                        const float* __restrict__ be,
                                                        float* __restrict__ ss) {
    __shared__ float red[1024];
    const int f = threadIdx.x & 127;
    const int seg = threadIdx.x >> 7;  // 0..7
    float s = 0.f;
    for (int b = seg; b < TILES; b += 8) s += partials[b * 128 + f];
    red[threadIdx.x] = s;
    __syncthreads();
    if (threadIdx.x < 128) {
        float tot = 0.f;
        #pragma unroll
        for (int k = 0; k < 8; ++k) tot += red[k * 128 + threadIdx.x];
        red[threadIdx.x] = tot;
    }
    __syncthreads();
    if (threadIdx.x < 64) {
        const float mean = red[threadIdx.x] * (1.0f / NN);
        const float var = red[64 + threadIdx.x] * (1.0f / NN) - mean * mean;
        const float scl = g[threadIdx.x] * rsqrtf(var + 1e-5f);
        ss[threadIdx.x] = scl;
        ss[64 + threadIdx.x] = be[threadIdx.x] - mean * scl;
    }
}

// ===========================================================================
// Pool with fused layer-3 affine: xpool[g] += scl.*t[r] + shift, batch sorted,
// atomics only at segment boundaries.
// ===========================================================================
__global__ __launch_bounds__(256) void pool_kernel(const float* __restrict__ t,
                                                   const int* __restrict__ batch,
                                                   const float* __restrict__ ss,
                                                   float* __restrict__ xpool) {
    const int wv = (blockIdx.x * 256 + threadIdx.x) >> 6;
    const int lane = threadIdx.x & 63;
    const int r0 = wv * 64;
    if (r0 >= NN) return;
    const int r1 = min(r0 + 64, NN);
    const float scl = ss[lane];
    const float sft = ss[64 + lane];
    int gprev = batch[r0];
    float acc = 0.f;
    for (int r = r0; r < r1; ++r) {
        const int g = batch[r];
        if (g != gprev) {
            __hip_atomic_fetch_add(&xpool[gprev * 64 + lane], acc,
                                   __ATOMIC_RELAXED, __HIP_MEMORY_SCOPE_AGENT);
            acc = 0.f;
            gprev = g;
        }
        acc += fmaf(t[r * 64 + lane], scl, sft);
    }
    __hip_atomic_fetch_add(&xpool[gprev * 64 + lane], acc,
                           __ATOMIC_RELAXED, __HIP_MEMORY_SCOPE_AGENT);
}

// ===========================================================================
// Head
// ===========================================================================
__global__ __launch_bounds__(256) void lin0_kernel(const float* __restrict__ xpool,
                                                   const float* __restrict__ w,
                                                   const float* __restrict__ b,
                                                   float* __restrict__ mid) {
    const int tid = blockIdx.x * blockDim.x + threadIdx.x;  // GG*128
    if (tid >= GG * 128) return;
    const int g = tid >> 7;
    const int m = tid & 127;
    float acc = b[m];
    #pragma unroll 8
    for (int k = 0; k < 64; ++k) acc = fmaf(xpool[g * 64 + k], w[k * 128 + m], acc);
    mid[tid] = acc;
}

__global__ __launch_bounds__(256) void fc1_kernel(const float* __restrict__ mid,
                                                  const float* __restrict__ w,
                                                  const float* __restrict__ b,
                                                  float* __restrict__ out) {
    const int tid = blockIdx.x * blockDim.x + threadIdx.x;  // GG*64
    if (tid >= GG * 64) return;
    const int g = tid >> 6;
    const int j = tid & 63;
    float acc = b[j];
    #pragma unroll 8
    for (int k = 0; k < 128; ++k) acc = fmaf(mid[g * 128 + k], w[k * 64 + j], acc);
    out[tid] = fmaxf(acc, 0.f);
}

extern "C" void kernel_launch(void* const* d_in, const int* in_sizes, int n_in,
                              void* d_out, int out_size, void* d_ws, size_t ws_size,
                              hipStream_t stream) {
    const float* x = (const float*)d_in[0];
    const int* ei = (const int*)d_in[1];
    const int* batch = (const int*)d_in[2];

    // ---- workspace layout (int region then 16B-aligned float region) ----
    int* ibase   = (int*)d_ws;
    int* counts  = ibase;            // 50000
    int* scanned = ibase + 50000;    // 50000
    int* rowptr  = ibase + 100000;   // 50001 (pad to 50004)
    int* cursor  = ibase + 150004;   // 50000
    int* bsum    = ibase + 200004;   // 124 (98 used)
    int* col     = ibase + 200128;   // 800000 -> int end 1,000,128
    float* fbase = (float*)d_ws + 1000128;  // byte 4,000,512 : 16B aligned
    float* z        = fbase;                // NN*64 = 3,200,000
    float* t        = z + 3200000;          // NN*64
    float* partials = t + 3200000;          // TILES*128 = 100,096
    float* ss       = partials + 100096;    // 128
    float* xpool    = ss + 128;             // GG*64 = 32768
    float* mid      = xpool + 32768;        // GG*128 = 65536

    // ---- CSR build (once, reused by all 3 layers) ----
    hipMemsetAsync(counts, 0, 50000 * sizeof(int), stream);
    hist_kernel<<<(EE + 255) / 256, 256, 0, stream>>>(ei, counts);
    scan1_kernel<<<SCAN_BLOCKS, 512, 0, stream>>>(counts, scanned, bsum);
    scan2_kernel<<<SCAN_BLOCKS, 512, 0, stream>>>(scanned, bsum, rowptr, cursor);
    fill_kernel<<<(EE + 255) / 256, 256, 0, stream>>>(ei, cursor, col);

    const float* hcur = x;
    for (int l = 0; l < 3; ++l) {
        const float* wa = (const float*)d_in[3 + l * 6 + 0];
        const float* ba = (const float*)d_in[3 + l * 6 + 1];
        const float* wb = (const float*)d_in[3 + l * 6 + 2];
        const float* bb = (const float*)d_in[3 + l * 6 + 3];
        const float* ga = (const float*)d_in[3 + l * 6 + 4];
        const float* be = (const float*)d_in[3 + l * 6 + 5];

        gather_kernel<<<1024, 256, 0, stream>>>(hcur, rowptr, col, ss, l > 0, z);
        mlp_kernel<<<TILES, 64, 0, stream>>>(z, wa, ba, wb, bb, t, partials);
        finalize_kernel<<<1, 1024, 0, stream>>>(partials, ga, be, ss);
        hcur = t;
    }

    hipMemsetAsync(xpool, 0, (size_t)GG * 64 * sizeof(float), stream);
    pool_kernel<<<(TILES + 3) / 4, 256, 0, stream>>>(t, batch, ss, xpool);
    lin0_kernel<<<(GG * 128 + 255) / 256, 256, 0, stream>>>(
        xpool, (const float*)d_in[21], (const float*)d_in[22], mid);
    fc1_kernel<<<(GG * 64 + 255) / 256, 256, 0, stream>>>(
        mid, (const float*)d_in[23], (const float*)d_in[24], (float*)d_out);
}